// Round 8
// baseline (1751.024 us; speedup 1.0000x reference)
//
#include <hip/hip_runtime.h>
#include <hip/hip_bf16.h>

#define SEQ    1024
#define DM     256
#define NH     8
#define NB     8
#define NLAYER 4
#define MLPD   1024
#define ROWS   (NB*SEQ)      // 8192
#define QKVW   6144          // 3*NH*DM
#define INNERW 2048          // NH*DM

typedef __attribute__((ext_vector_type(8))) short bh8;
typedef __attribute__((ext_vector_type(4))) short bh4;
typedef __attribute__((ext_vector_type(4))) float fx4;

__device__ __forceinline__ short f2bf(float f) {
  return __builtin_bit_cast(short, __float2bfloat16(f));
}
__device__ __forceinline__ fx4 mfma16(bh8 a, bh8 b, fx4 c) {
  return __builtin_amdgcn_mfma_f32_16x16x32_bf16(a, b, c, 0, 0, 0);
}
__device__ __forceinline__ void g2l16(const void* g, void* l) {
  __builtin_amdgcn_global_load_lds(
      (const __attribute__((address_space(1))) void*)g,
      (__attribute__((address_space(3))) void*)l, 16, 0, 0);
}

// ---------------- f32 copy (x -> xf, xf -> out) ----------------
__global__ void copy_f32_k(const float* __restrict__ src, float* __restrict__ dst) {
  size_t i = ((size_t)blockIdx.x * 256 + threadIdx.x) * 4;
  *(fx4*)(dst + i) = *(const fx4*)(src + i);
}

// ---------------- f32 -> bf16 transpose (per-layer via blockIdx.z) ----------------
// src: [R][C] f32 (row stride C), dst: [C][R] bf16
__global__ void wtrans_k(const float* __restrict__ src, __hip_bfloat16* __restrict__ dst,
                         int R, int C, size_t sls, size_t dls) {
  src += (size_t)blockIdx.z * sls;
  dst += (size_t)blockIdx.z * dls;
  __shared__ float t[32][33];
  int tx = threadIdx.x, ty = threadIdx.y;
  int r0 = blockIdx.y * 32, c0 = blockIdx.x * 32;
#pragma unroll
  for (int i = 0; i < 32; i += 8) t[ty + i][tx] = src[(size_t)(r0 + ty + i) * C + c0 + tx];
  __syncthreads();
#pragma unroll
  for (int i = 0; i < 32; i += 8)
    dst[(size_t)(c0 + ty + i) * R + r0 + tx] = __float2bfloat16(t[tx][ty + i]);
}

// V part of qkv (bf16) -> vT[b][h][d][n] (bf16), with key order inside each
// 32-key block permuted to match the PV A-fragment order:
//   slot(k) = ((k>>2)&3)*8 + (k&3) + (((k>>4)&1)<<2)   (k = key within 32-block)
// 64x64 tiles: 128-B contiguous segments on both read and write sides
// (the slot permutation stays inside a 64-B segment, so writes still coalesce).
__global__ void vtrans_k(const __hip_bfloat16* __restrict__ qkv, __hip_bfloat16* __restrict__ vT) {
  int bh = blockIdx.z, b = bh >> 3, hh = bh & 7;
  const __hip_bfloat16* src = qkv + (size_t)b * SEQ * QKVW + 4096 + hh * 256; // [n][d], ld QKVW
  __hip_bfloat16* dst = vT + (size_t)bh * 256 * SEQ;                          // [d][n], ld SEQ
  __shared__ __hip_bfloat16 t[64][65];
  int tx = threadIdx.x, ty = threadIdx.y;   // (64, 8)
  int n0 = blockIdx.x * 64, d0 = blockIdx.y * 64;
#pragma unroll
  for (int i = 0; i < 64; i += 8) t[ty + i][tx] = src[(size_t)(n0 + ty + i) * QKVW + d0 + tx];
  __syncthreads();
  int slot = (tx & 32) + ((tx >> 2) & 3) * 8 + (tx & 3) + (((tx >> 4) & 1) << 2);
#pragma unroll
  for (int i = 0; i < 64; i += 8) dst[(size_t)(d0 + ty + i) * SEQ + n0 + slot] = t[tx][ty + i];
}

// ---------------- LayerNorm over axis=1 (sequence), per-(b,d) stats ----------------
// grid (DM/8, NB) = 256 blocks, block 256
__global__ void ln_k(const float* __restrict__ xf, const float* __restrict__ gam,
                     const float* __restrict__ bet, __hip_bfloat16* __restrict__ h) {
  int b = blockIdx.y, d0 = blockIdx.x * 8;
  int dl = threadIdx.x & 7;
  int nt = threadIdx.x >> 3;   // 0..31
  int d = d0 + dl;
  const float* xb = xf + (size_t)b * SEQ * DM;
  float s = 0.f, ss = 0.f;
  for (int n = nt; n < SEQ; n += 32) {
    float v = xb[(size_t)n * DM + d];
    s += v; ss += v * v;
  }
  __shared__ float S1[32][8], S2[32][8];
  __shared__ float MU[8], RS[8];
  S1[nt][dl] = s; S2[nt][dl] = ss;
  __syncthreads();
  if (nt == 0) {
    float a = 0.f, c = 0.f;
#pragma unroll
    for (int i = 0; i < 32; i++) { a += S1[i][dl]; c += S2[i][dl]; }
    float mu = a * (1.f / SEQ);
    float var = c * (1.f / SEQ) - mu * mu;
    MU[dl] = mu; RS[dl] = rsqrtf(var + 1e-3f);
  }
  __syncthreads();
  float mu = MU[dl], rs = RS[dl];
  __hip_bfloat16* hb = h + (size_t)b * SEQ * DM;
  for (int n = nt; n < SEQ; n += 32) {
    float v = (xb[(size_t)n * DM + d] - mu) * rs * gam[n] + bet[n];
    hb[(size_t)n * DM + d] = __float2bfloat16(v);
  }
}

// ---------------- GEMM: C[M,Nc] = A[M,K] * Bt[Nc,K]^T  (+ epilogues) ----------------
// BK=64 (32 MFMA per barrier-pair), LDS XOR-swizzled at 16B granularity.
// XCD-aware bijective block swizzle (T1). Direct-store epilogue.
// EPI 0: store bf16   EPI 1: +bias(f32), exact GELU, store bf16   EPI 2: resid[f32] += acc + bias
template <int BN, int EPI>
__global__ __launch_bounds__(256) void gemm_bt(
    const __hip_bfloat16* __restrict__ A, const __hip_bfloat16* __restrict__ Bt,
    __hip_bfloat16* __restrict__ Cout, const float* __restrict__ bias,
    float* __restrict__ resid, int M, int Nc, int K) {
  constexpr int BM = 128, BK = 64;
  constexpr int NR = BN / 32;
  static_assert(BN == 64 || BN == 128, "");
  __shared__ __hip_bfloat16 As[BM * BK];
  __shared__ __hip_bfloat16 Bs[BN * BK];
  const int tid = threadIdx.x;
  const int lane = tid & 63, w = tid >> 6;
  const int g = lane >> 4, qr = lane & 15;
  const int wr = w >> 1, wc = w & 1;
  // XCD swizzle: apparent id -> logical id so each XCD gets a contiguous chunk
  const unsigned aid = blockIdx.y * gridDim.x + blockIdx.x;
  const unsigned nwg = gridDim.x * gridDim.y;
  const unsigned lid = (aid & 7u) * (nwg >> 3) + (aid >> 3);
  const int m0 = (int)(lid / gridDim.x) * BM, n0 = (int)(lid % gridDim.x) * BN;
  const int swr = qr & 7;

  fx4 acc[4][NR];
#pragma unroll
  for (int m = 0; m < 4; m++)
#pragma unroll
    for (int n = 0; n < NR; n++) acc[m][n] = 0.f;

  constexpr int ACH = (BM * BK) / (8 * 256); // 4
  constexpr int BCH = (BN * BK) / (8 * 256); // 4 or 2

  for (int k0 = 0; k0 < K; k0 += BK) {
    __syncthreads();
#pragma unroll
    for (int c = 0; c < ACH; c++) {
      int idx = tid + c * 256;
      int row = idx >> 3, gr2 = idx & 7;
      g2l16(A + (size_t)(m0 + row) * K + k0 + ((gr2 ^ (row & 7)) << 3), (char*)As + idx * 16);
    }
#pragma unroll
    for (int c = 0; c < BCH; c++) {
      int idx = tid + c * 256;
      int col = idx >> 3, gr2 = idx & 7;
      g2l16(Bt + (size_t)(n0 + col) * K + k0 + ((gr2 ^ (col & 7)) << 3), (char*)Bs + idx * 16);
    }
    __syncthreads();
#pragma unroll
    for (int ks = 0; ks < 2; ks++) {
      bh8 af[4], bf[NR];
#pragma unroll
      for (int m = 0; m < 4; m++)
        af[m] = *(const bh8*)(As + (wr * 64 + m * 16 + qr) * BK + (((ks * 4 + g) ^ swr) << 3));
#pragma unroll
      for (int n = 0; n < NR; n++)
        bf[n] = *(const bh8*)(Bs + (wc * (BN / 2) + n * 16 + qr) * BK + (((ks * 4 + g) ^ swr) << 3));
#pragma unroll
      for (int m = 0; m < 4; m++)
#pragma unroll
        for (int n = 0; n < NR; n++) acc[m][n] = mfma16(af[m], bf[n], acc[m][n]);
    }
  }

#pragma unroll
  for (int n = 0; n < NR; n++) {
    int gc = n0 + wc * (BN / 2) + n * 16 + qr;
    float bv = (EPI >= 1) ? bias[gc] : 0.f;
#pragma unroll
    for (int m = 0; m < 4; m++) {
      int grb = m0 + wr * 64 + m * 16 + g * 4;
#pragma unroll
      for (int r = 0; r < 4; r++) {
        float v = acc[m][n][r];
        int gr = grb + r;
        if (EPI == 0) {
          Cout[(size_t)gr * Nc + gc] = __float2bfloat16(v);
        } else if (EPI == 1) {
          v += bv;
          v = 0.5f * v * (1.f + erff(v * 0.70710678118654752f));
          Cout[(size_t)gr * Nc + gc] = __float2bfloat16(v);
        } else {
          resid[(size_t)gr * Nc + gc] += v + bv;
        }
      }
    }
  }
}

// ---------------- Flash attention: grid (SEQ/64, NH, NB), 4 waves x 16 q-rows ----------------
// v8: K is read DIRECTLY from global/L2 per-wave (same per-lane pattern as the Q
// loads; K is L2-resident after the XCD swizzle) — this halves the LDS-pipe load
// (the measured dominant resource: 16 waves/CU x 32 b128/tile ~ 5100 cyc/tile-step)
// and frees 16 KB LDS, which double-buffers V in the SAME 32 KB footprint
// (occupancy stays 4 blocks/CU). T3-minimum pipeline: stage V(t+1) first, compute
// QK+softmax+PV on V(t), ONE __syncthreads per iter — its vmcnt(0) drain of the
// V-stage is hidden behind the whole compute phase.
// Vs: [d 0..255][32 key-slots] (slots PV-permuted by vtrans_k), granule G ^= (d>>1)&3,
// global source pre-swizzled (rule #21). Softmax: defer-max + exp2-domain.
__global__ __launch_bounds__(256) void attn_k(
    const __hip_bfloat16* __restrict__ qkv, const __hip_bfloat16* __restrict__ vT,
    __hip_bfloat16* __restrict__ z) {
  __shared__ __hip_bfloat16 Vs[2][256 * 32];
  const int tid = threadIdx.x;
  const int lane = tid & 63, w = tid >> 6;
  const int g = lane >> 4, qr = lane & 15;
  // XCD swizzle: nwg = 16*8*8 = 1024, chunk = 128 logical blocks per XCD
  const unsigned aid = (blockIdx.z * NH + blockIdx.y) * (SEQ / 64) + blockIdx.x;
  const unsigned lid = (aid & 7u) * 128u + (aid >> 3);
  const int qi = lid & 15, hh = (lid >> 4) & 7, b = lid >> 7;
  const int q0 = qi * 64 + w * 16;
  const size_t qkv_b = (size_t)b * SEQ * QKVW;

  // Q fragments: lane holds Q[q0+qr][kd*32 + g*8 .. +8]
  bh8 qf[8];
  {
    const __hip_bfloat16* qrow = qkv + qkv_b + (size_t)(q0 + qr) * QKVW + hh * 256 + g * 8;
#pragma unroll
    for (int kd = 0; kd < 8; kd++) qf[kd] = *(const bh8*)(qrow + kd * 32);
  }
  // K row base pointers for this lane (rows qr and 16+qr of each 32-key tile)
  const __hip_bfloat16* kb = qkv + qkv_b + 2048 + hh * 256 + g * 8;
  const __hip_bfloat16* vbase = vT + ((size_t)(b * 8 + hh) * 256) * SEQ;

  fx4 o[16];
#pragma unroll
  for (int i = 0; i < 16; i++) o[i] = 0.f;
  float m_run = -INFINITY, l_run = 0.f;        // m_run in RAW score units
  constexpr float cL = 0.0625f * 1.44269504f;  // scale * log2(e)

  const int vsw = ((qr >> 1) & 3);        // Vs read swizzle (d = nd*16+qr -> (d>>1)&3)

  auto stageV = [&](int bb, int j0) {
#pragma unroll
    for (int c = 0; c < 4; c++) {
      int idx = tid + c * 256;
      int d = idx >> 2, gr = idx & 3;
      int np = (gr ^ ((d >> 1) & 3)) << 3; // pre-swizzled source slot (elements)
      g2l16(vbase + (size_t)d * SEQ + j0 + np, (char*)Vs[bb] + idx * 16);
    }
  };

  stageV(0, 0);
  __syncthreads();

  for (int jt = 0; jt < SEQ / 32; ++jt) {
    const int j0 = jt * 32;
    const int cur = jt & 1;
    if (jt < SEQ / 32 - 1) stageV(cur ^ 1, j0 + 32);  // hidden behind this iter's compute

    // S^T = K * Q^T : lane holds S[q=qr][key = {g*4+r, 16+g*4+r}]  (raw scores)
    // K fragments straight from global (L2-hot): rows j0+qr and j0+16+qr.
    const __hip_bfloat16* krow0 = kb + (size_t)(j0 + qr) * QKVW;
    const __hip_bfloat16* krow1 = krow0 + (size_t)16 * QKVW;
    fx4 s0 = 0.f, s1 = 0.f;
#pragma unroll
    for (int kd = 0; kd < 8; kd++) {
      bh8 k0f = *(const bh8*)(krow0 + kd * 32);
      bh8 k1f = *(const bh8*)(krow1 + kd * 32);
      s0 = mfma16(k0f, qf[kd], s0);
      s1 = mfma16(k1f, qf[kd], s1);
    }
    float sv[8];
#pragma unroll
    for (int r = 0; r < 4; r++) { sv[r] = s0[r]; sv[4 + r] = s1[r]; }
    float pmax = sv[0];
#pragma unroll
    for (int i = 1; i < 8; i++) pmax = fmaxf(pmax, sv[i]);
    pmax = fmaxf(pmax, __shfl_xor(pmax, 16));
    pmax = fmaxf(pmax, __shfl_xor(pmax, 32));
    // defer-max: rescale only if some row's max grew by > 128 raw (= 8 scaled)
    if (!__all(pmax <= m_run + 128.f)) {
      float m_new = fmaxf(m_run, pmax);
      float corr = __builtin_amdgcn_exp2f((m_run - m_new) * cL); // first tile: 0
      float co[4];
#pragma unroll
      for (int r = 0; r < 4; r++) co[r] = __shfl(corr, (lane & 48) | (g * 4 + r));
#pragma unroll
      for (int nd = 0; nd < 16; nd++) {
        o[nd][0] *= co[0]; o[nd][1] *= co[1]; o[nd][2] *= co[2]; o[nd][3] *= co[3];
      }
      l_run *= corr;
      m_run = m_new;
    }
    float mL = m_run * cL;
    float p[8], ps = 0.f;
#pragma unroll
    for (int i = 0; i < 8; i++) {
      p[i] = __builtin_amdgcn_exp2f(fmaf(sv[i], cL, -mL)); // bounded by 2^8
      ps += p[i];
    }
    ps += __shfl_xor(ps, 16);
    ps += __shfl_xor(ps, 32);
    l_run += ps;
    // P -> bf16 A-frag with key(g,i) = g*4 + (i&3) + 16*(i>>2); Vs slots hold V in the
    // same key order, so the B-fragment is ONE bh8 read (swizzled).
    bh8 pa;
#pragma unroll
    for (int i = 0; i < 8; i++) pa[i] = f2bf(p[i]);
#pragma unroll
    for (int nd = 0; nd < 16; nd++) {
      int d = nd * 16 + qr;
      bh8 vf = *(const bh8*)(Vs[cur] + (size_t)d * 32 + ((g ^ vsw) << 3));
      o[nd] = mfma16(pa, vf, o[nd]);
    }
    // single barrier per iter: drains the V(t+1) stage (hidden by the compute above)
    // and guarantees all waves finished reading Vs[cur] before it is re-staged.
    __syncthreads();
  }

  float inv = 1.f / l_run;
  float io[4];
#pragma unroll
  for (int r = 0; r < 4; r++) io[r] = __shfl(inv, (lane & 48) | (g * 4 + r));
  __hip_bfloat16* zb = z + (size_t)b * SEQ * INNERW + hh * 256;
#pragma unroll
  for (int nd = 0; nd < 16; nd++)
#pragma unroll
    for (int r = 0; r < 4; r++)
      zb[(size_t)(q0 + g * 4 + r) * INNERW + nd * 16 + qr] = __float2bfloat16(o[nd][r] * io[r]);
}

// ---------------- host ----------------
extern "C" void kernel_launch(void* const* d_in, const int* in_sizes, int n_in,
                              void* d_out, int out_size, void* d_ws, size_t ws_size,
                              hipStream_t stream) {
  const float* x_in  = (const float*)d_in[0];
  const float* ln1g  = (const float*)d_in[1];
  const float* ln1b  = (const float*)d_in[2];
  const float* w_qkv = (const float*)d_in[3];
  const float* w_out = (const float*)d_in[4];
  const float* b_out = (const float*)d_in[5];
  const float* ln2g  = (const float*)d_in[6];
  const float* ln2b  = (const float*)d_in[7];
  const float* w1    = (const float*)d_in[8];
  const float* b1    = (const float*)d_in[9];
  const float* w2    = (const float*)d_in[10];
  const float* b2    = (const float*)d_in[11];

  char* ws = (char*)d_ws;
  size_t off = 0;
  auto alloc = [&](size_t bytes) { char* p = ws + off; off += (bytes + 255) & ~(size_t)255; return p; };
  float*          xf    = (float*)         alloc((size_t)ROWS * DM * 4);
  __hip_bfloat16* h     = (__hip_bfloat16*)alloc((size_t)ROWS * DM * 2);
  __hip_bfloat16* qkv   = (__hip_bfloat16*)alloc((size_t)ROWS * QKVW * 2);
  __hip_bfloat16* vT    = (__hip_bfloat16*)alloc((size_t)NB * NH * 256 * SEQ * 2);
  __hip_bfloat16* zbuf  = (__hip_bfloat16*)alloc((size_t)ROWS * INNERW * 2);
  __hip_bfloat16* mh    = zbuf; // MLP hidden reuses z region (disjoint lifetimes)
  __hip_bfloat16* wqkvT = (__hip_bfloat16*)alloc((size_t)NLAYER * QKVW * DM * 2);
  __hip_bfloat16* woutT = (__hip_bfloat16*)alloc((size_t)NLAYER * DM * INNERW * 2);
  __hip_bfloat16* w1T   = (__hip_bfloat16*)alloc((size_t)NLAYER * MLPD * DM * 2);
  __hip_bfloat16* w2T   = (__hip_bfloat16*)alloc((size_t)NLAYER * DM * MLPD * 2);
  (void)ws_size; (void)in_sizes; (void)n_in; (void)out_size;

  copy_f32_k<<<2048, 256, 0, stream>>>(x_in, xf);

  // weight transposes+casts (weights constant across the launch)
  wtrans_k<<<dim3(QKVW / 32, DM / 32, NLAYER), dim3(32, 8), 0, stream>>>(
      w_qkv, wqkvT, DM, QKVW, (size_t)DM * QKVW, (size_t)DM * QKVW);
  wtrans_k<<<dim3(DM / 32, INNERW / 32, NLAYER), dim3(32, 8), 0, stream>>>(
      w_out, woutT, INNERW, DM, (size_t)INNERW * DM, (size_t)INNERW * DM);
  wtrans_k<<<dim3(MLPD / 32, DM / 32, NLAYER), dim3(32, 8), 0, stream>>>(
      w1, w1T, DM, MLPD, (size_t)DM * MLPD, (size_t)DM * MLPD);
  wtrans_k<<<dim3(DM / 32, MLPD / 32, NLAYER), dim3(32, 8), 0, stream>>>(
      w2, w2T, MLPD, DM, (size_t)MLPD * DM, (size_t)MLPD * DM);

  for (int i = 0; i < NLAYER; i++) {
    ln_k<<<dim3(DM / 8, NB), 256, 0, stream>>>(xf, ln1g + i * SEQ, ln1b + i * SEQ, h);
    gemm_bt<128, 0><<<dim3(QKVW / 128, ROWS / 128), 256, 0, stream>>>(
        h, wqkvT + (size_t)i * QKVW * DM, qkv, nullptr, nullptr, ROWS, QKVW, DM);
    vtrans_k<<<dim3(SEQ / 64, 256 / 64, NB * NH), dim3(64, 8), 0, stream>>>(qkv, vT);
    attn_k<<<dim3(SEQ / 64, NH, NB), 256, 0, stream>>>(qkv, vT, zbuf);
    gemm_bt<64, 2><<<dim3(DM / 64, ROWS / 128), 256, 0, stream>>>(
        zbuf, woutT + (size_t)i * DM * INNERW, nullptr, b_out + i * DM, xf, ROWS, DM, INNERW);
    ln_k<<<dim3(DM / 8, NB), 256, 0, stream>>>(xf, ln2g + i * SEQ, ln2b + i * SEQ, h);
    gemm_bt<128, 1><<<dim3(MLPD / 128, ROWS / 128), 256, 0, stream>>>(
        h, w1T + (size_t)i * MLPD * DM, mh, b1 + i * MLPD, nullptr, ROWS, MLPD, DM);
    gemm_bt<64, 2><<<dim3(DM / 64, ROWS / 128), 256, 0, stream>>>(
        mh, w2T + (size_t)i * DM * MLPD, nullptr, b2 + i * DM, xf, ROWS, DM, MLPD);
  }

  copy_f32_k<<<2048, 256, 0, stream>>>(xf, (float*)d_out);
}

// Round 9
// 1150.390 us; speedup vs baseline: 1.5221x; 1.5221x over previous
//
#include <hip/hip_runtime.h>
#include <hip/hip_bf16.h>

#define SEQ    1024
#define DM     256
#define NH     8
#define NB     8
#define NLAYER 4
#define MLPD   1024
#define ROWS   (NB*SEQ)      // 8192
#define QKVW   6144          // 3*NH*DM
#define INNERW 2048          // NH*DM

typedef __attribute__((ext_vector_type(8))) short bh8;
typedef __attribute__((ext_vector_type(4))) short bh4;
typedef __attribute__((ext_vector_type(4))) float fx4;

__device__ __forceinline__ short f2bf(float f) {
  return __builtin_bit_cast(short, __float2bfloat16(f));
}
__device__ __forceinline__ fx4 mfma16(bh8 a, bh8 b, fx4 c) {
  return __builtin_amdgcn_mfma_f32_16x16x32_bf16(a, b, c, 0, 0, 0);
}
__device__ __forceinline__ void g2l16(const void* g, void* l) {
  __builtin_amdgcn_global_load_lds(
      (const __attribute__((address_space(1))) void*)g,
      (__attribute__((address_space(3))) void*)l, 16, 0, 0);
}
// V-style granule permutation: 8 consecutive lanes hit bank-slots in the
// alternating order (0,4,1,5,...) that is empirically conflict-free on gfx950
// (R8 diagnostic: V reads with this structure = 0 conflicts; sequential-order
// K reads = 4 extra cycles each, 2^23 total).
__device__ __forceinline__ int kperm(int r) {
  return ((r & 1) << 2) | ((r >> 1) & 3);
}

// ---------------- f32 copy (x -> xf, xf -> out) ----------------
__global__ void copy_f32_k(const float* __restrict__ src, float* __restrict__ dst) {
  size_t i = ((size_t)blockIdx.x * 256 + threadIdx.x) * 4;
  *(fx4*)(dst + i) = *(const fx4*)(src + i);
}

// ---------------- f32 -> bf16 transpose (per-layer via blockIdx.z) ----------------
// src: [R][C] f32 (row stride C), dst: [C][R] bf16
__global__ void wtrans_k(const float* __restrict__ src, __hip_bfloat16* __restrict__ dst,
                         int R, int C, size_t sls, size_t dls) {
  src += (size_t)blockIdx.z * sls;
  dst += (size_t)blockIdx.z * dls;
  __shared__ float t[32][33];
  int tx = threadIdx.x, ty = threadIdx.y;
  int r0 = blockIdx.y * 32, c0 = blockIdx.x * 32;
#pragma unroll
  for (int i = 0; i < 32; i += 8) t[ty + i][tx] = src[(size_t)(r0 + ty + i) * C + c0 + tx];
  __syncthreads();
#pragma unroll
  for (int i = 0; i < 32; i += 8)
    dst[(size_t)(c0 + ty + i) * R + r0 + tx] = __float2bfloat16(t[tx][ty + i]);
}

// V part of qkv (bf16) -> vT[b][h][d][n] (bf16), with key order inside each
// 32-key block permuted to match the PV A-fragment order:
//   slot(k) = ((k>>2)&3)*8 + (k&3) + (((k>>4)&1)<<2)   (k = key within 32-block)
// 64x64 tiles: 128-B contiguous segments on both read and write sides.
__global__ void vtrans_k(const __hip_bfloat16* __restrict__ qkv, __hip_bfloat16* __restrict__ vT) {
  int bh = blockIdx.z, b = bh >> 3, hh = bh & 7;
  const __hip_bfloat16* src = qkv + (size_t)b * SEQ * QKVW + 4096 + hh * 256; // [n][d], ld QKVW
  __hip_bfloat16* dst = vT + (size_t)bh * 256 * SEQ;                          // [d][n], ld SEQ
  __shared__ __hip_bfloat16 t[64][65];
  int tx = threadIdx.x, ty = threadIdx.y;   // (64, 8)
  int n0 = blockIdx.x * 64, d0 = blockIdx.y * 64;
#pragma unroll
  for (int i = 0; i < 64; i += 8) t[ty + i][tx] = src[(size_t)(n0 + ty + i) * QKVW + d0 + tx];
  __syncthreads();
  int slot = (tx & 32) + ((tx >> 2) & 3) * 8 + (tx & 3) + (((tx >> 4) & 1) << 2);
#pragma unroll
  for (int i = 0; i < 64; i += 8) dst[(size_t)(d0 + ty + i) * SEQ + n0 + slot] = t[tx][ty + i];
}

// ---------------- LayerNorm over axis=1 (sequence), per-(b,d) stats ----------------
// grid (DM/8, NB) = 256 blocks, block 256
__global__ void ln_k(const float* __restrict__ xf, const float* __restrict__ gam,
                     const float* __restrict__ bet, __hip_bfloat16* __restrict__ h) {
  int b = blockIdx.y, d0 = blockIdx.x * 8;
  int dl = threadIdx.x & 7;
  int nt = threadIdx.x >> 3;   // 0..31
  int d = d0 + dl;
  const float* xb = xf + (size_t)b * SEQ * DM;
  float s = 0.f, ss = 0.f;
  for (int n = nt; n < SEQ; n += 32) {
    float v = xb[(size_t)n * DM + d];
    s += v; ss += v * v;
  }
  __shared__ float S1[32][8], S2[32][8];
  __shared__ float MU[8], RS[8];
  S1[nt][dl] = s; S2[nt][dl] = ss;
  __syncthreads();
  if (nt == 0) {
    float a = 0.f, c = 0.f;
#pragma unroll
    for (int i = 0; i < 32; i++) { a += S1[i][dl]; c += S2[i][dl]; }
    float mu = a * (1.f / SEQ);
    float var = c * (1.f / SEQ) - mu * mu;
    MU[dl] = mu; RS[dl] = rsqrtf(var + 1e-3f);
  }
  __syncthreads();
  float mu = MU[dl], rs = RS[dl];
  __hip_bfloat16* hb = h + (size_t)b * SEQ * DM;
  for (int n = nt; n < SEQ; n += 32) {
    float v = (xb[(size_t)n * DM + d] - mu) * rs * gam[n] + bet[n];
    hb[(size_t)n * DM + d] = __float2bfloat16(v);
  }
}

// ---------------- GEMM: C[M,Nc] = A[M,K] * Bt[Nc,K]^T  (+ epilogues) ----------------
// BK=64 (32 MFMA per barrier-pair), LDS swizzled with the V-style kperm bijection
// (both stage source and read — rule #21). XCD-aware bijective block swizzle (T1).
// EPI 0: store bf16   EPI 1: +bias(f32), exact GELU, store bf16   EPI 2: resid[f32] += acc + bias
template <int BN, int EPI>
__global__ __launch_bounds__(256) void gemm_bt(
    const __hip_bfloat16* __restrict__ A, const __hip_bfloat16* __restrict__ Bt,
    __hip_bfloat16* __restrict__ Cout, const float* __restrict__ bias,
    float* __restrict__ resid, int M, int Nc, int K) {
  constexpr int BM = 128, BK = 64;
  constexpr int NR = BN / 32;
  static_assert(BN == 64 || BN == 128, "");
  __shared__ __hip_bfloat16 As[BM * BK];
  __shared__ __hip_bfloat16 Bs[BN * BK];
  const int tid = threadIdx.x;
  const int lane = tid & 63, w = tid >> 6;
  const int g = lane >> 4, qr = lane & 15;
  const int wr = w >> 1, wc = w & 1;
  // XCD swizzle: apparent id -> logical id so each XCD gets a contiguous chunk
  const unsigned aid = blockIdx.y * gridDim.x + blockIdx.x;
  const unsigned nwg = gridDim.x * gridDim.y;
  const unsigned lid = (aid & 7u) * (nwg >> 3) + (aid >> 3);
  const int m0 = (int)(lid / gridDim.x) * BM, n0 = (int)(lid % gridDim.x) * BN;
  const int swr = kperm(qr & 7);

  fx4 acc[4][NR];
#pragma unroll
  for (int m = 0; m < 4; m++)
#pragma unroll
    for (int n = 0; n < NR; n++) acc[m][n] = 0.f;

  constexpr int ACH = (BM * BK) / (8 * 256); // 4
  constexpr int BCH = (BN * BK) / (8 * 256); // 4 or 2

  for (int k0 = 0; k0 < K; k0 += BK) {
    __syncthreads();
#pragma unroll
    for (int c = 0; c < ACH; c++) {
      int idx = tid + c * 256;
      int row = idx >> 3, gr2 = idx & 7;
      g2l16(A + (size_t)(m0 + row) * K + k0 + ((gr2 ^ kperm(row & 7)) << 3), (char*)As + idx * 16);
    }
#pragma unroll
    for (int c = 0; c < BCH; c++) {
      int idx = tid + c * 256;
      int col = idx >> 3, gr2 = idx & 7;
      g2l16(Bt + (size_t)(n0 + col) * K + k0 + ((gr2 ^ kperm(col & 7)) << 3), (char*)Bs + idx * 16);
    }
    __syncthreads();
#pragma unroll
    for (int ks = 0; ks < 2; ks++) {
      bh8 af[4], bf[NR];
#pragma unroll
      for (int m = 0; m < 4; m++)
        af[m] = *(const bh8*)(As + (wr * 64 + m * 16 + qr) * BK + (((ks * 4 + g) ^ swr) << 3));
#pragma unroll
      for (int n = 0; n < NR; n++)
        bf[n] = *(const bh8*)(Bs + (wc * (BN / 2) + n * 16 + qr) * BK + (((ks * 4 + g) ^ swr) << 3));
#pragma unroll
      for (int m = 0; m < 4; m++)
#pragma unroll
        for (int n = 0; n < NR; n++) acc[m][n] = mfma16(af[m], bf[n], acc[m][n]);
    }
  }

#pragma unroll
  for (int n = 0; n < NR; n++) {
    int gc = n0 + wc * (BN / 2) + n * 16 + qr;
    float bv = (EPI >= 1) ? bias[gc] : 0.f;
#pragma unroll
    for (int m = 0; m < 4; m++) {
      int grb = m0 + wr * 64 + m * 16 + g * 4;
#pragma unroll
      for (int r = 0; r < 4; r++) {
        float v = acc[m][n][r];
        int gr = grb + r;
        if (EPI == 0) {
          Cout[(size_t)gr * Nc + gc] = __float2bfloat16(v);
        } else if (EPI == 1) {
          v += bv;
          v = 0.5f * v * (1.f + erff(v * 0.70710678118654752f));
          Cout[(size_t)gr * Nc + gc] = __float2bfloat16(v);
        } else {
          resid[(size_t)gr * Nc + gc] += v + bv;
        }
      }
    }
  }
}

// ---------------- Flash attention: grid (SEQ/64, NH, NB), 4 waves x 16 q-rows ----------------
// R5-exact structure (best measured 125.7 µs): single-buffered Ks/Vs, 256 threads,
// 4 blocks/CU, XCD-aware bijective swizzle. This round: K granule permutation
// switched from (row&7) to kperm(row) — the V-style alternating slot order that
// R8 proved conflict-free (V-only LDS => SQ_LDS_BANK_CONFLICT = 0).
//   Ks: [key 0..31][256 d], granule G holds data granule G ^ kperm(key&7)
//   Vs: [d 0..255][32 key-slots] (slots PV-permuted by vtrans_k), G ^= (d>>1)&3
// Softmax: defer-max (THR=128 raw = 8 scaled) + exp2-domain.
__global__ __launch_bounds__(256) void attn_k(
    const __hip_bfloat16* __restrict__ qkv, const __hip_bfloat16* __restrict__ vT,
    __hip_bfloat16* __restrict__ z) {
  __shared__ __hip_bfloat16 Ks[32 * 256];
  __shared__ __hip_bfloat16 Vs[256 * 32];
  const int tid = threadIdx.x;
  const int lane = tid & 63, w = tid >> 6;
  const int g = lane >> 4, qr = lane & 15;
  // XCD swizzle: nwg = 16*8*8 = 1024, chunk = 128 logical blocks per XCD
  const unsigned aid = (blockIdx.z * NH + blockIdx.y) * (SEQ / 64) + blockIdx.x;
  const unsigned lid = (aid & 7u) * 128u + (aid >> 3);
  const int qi = lid & 15, hh = (lid >> 4) & 7, b = lid >> 7;
  const int q0 = qi * 64 + w * 16;
  const size_t qkv_b = (size_t)b * SEQ * QKVW;

  // Q fragments: lane holds Q[q0+qr][kd*32 + g*8 .. +8]
  bh8 qf[8];
  {
    const __hip_bfloat16* qrow = qkv + qkv_b + (size_t)(q0 + qr) * QKVW + hh * 256 + g * 8;
#pragma unroll
    for (int kd = 0; kd < 8; kd++) qf[kd] = *(const bh8*)(qrow + kd * 32);
  }

  fx4 o[16];
#pragma unroll
  for (int i = 0; i < 16; i++) o[i] = 0.f;
  float m_run = -INFINITY, l_run = 0.f;        // m_run in RAW score units
  constexpr float cL = 0.0625f * 1.44269504f;  // scale * log2(e)

  const int ksw = kperm(qr & 7);          // Ks read swizzle (rows qr and 16+qr share it)
  const int vsw = ((qr >> 1) & 3);        // Vs read swizzle (d = nd*16+qr -> (d>>1)&3)

  for (int j0 = 0; j0 < SEQ; j0 += 32) {
    __syncthreads();
#pragma unroll
    for (int c = 0; c < 4; c++) {
      int idx = tid + c * 256;
      int key = idx >> 5, c16 = idx & 31;
      int dp = (c16 ^ kperm(key & 7)) << 3; // pre-swizzled source column (elements)
      g2l16(qkv + qkv_b + (size_t)(j0 + key) * QKVW + 2048 + hh * 256 + dp, (char*)Ks + idx * 16);
    }
    const __hip_bfloat16* vb = vT + ((size_t)(b * 8 + hh) * 256) * SEQ + j0;
#pragma unroll
    for (int c = 0; c < 4; c++) {
      int idx = tid + c * 256;
      int d = idx >> 2, gr = idx & 3;
      int np = (gr ^ ((d >> 1) & 3)) << 3; // pre-swizzled source slot (elements)
      g2l16(vb + (size_t)d * SEQ + np, (char*)Vs + idx * 16);
    }
    __syncthreads();

    // S^T = K * Q^T : lane holds S[q=qr][key = {g*4+r, 16+g*4+r}]  (raw scores)
    fx4 s0 = 0.f, s1 = 0.f;
#pragma unroll
    for (int kd = 0; kd < 8; kd++) {
      bh8 k0f = *(const bh8*)(Ks + (size_t)qr * 256 + (((kd * 4 + g) ^ ksw) << 3));
      bh8 k1f = *(const bh8*)(Ks + (size_t)(16 + qr) * 256 + (((kd * 4 + g) ^ ksw) << 3));
      s0 = mfma16(k0f, qf[kd], s0);
      s1 = mfma16(k1f, qf[kd], s1);
    }
    float sv[8];
#pragma unroll
    for (int r = 0; r < 4; r++) { sv[r] = s0[r]; sv[4 + r] = s1[r]; }
    float pmax = sv[0];
#pragma unroll
    for (int i = 1; i < 8; i++) pmax = fmaxf(pmax, sv[i]);
    pmax = fmaxf(pmax, __shfl_xor(pmax, 16));
    pmax = fmaxf(pmax, __shfl_xor(pmax, 32));
    // defer-max: rescale only if some row's max grew by > 128 raw (= 8 scaled)
    if (!__all(pmax <= m_run + 128.f)) {
      float m_new = fmaxf(m_run, pmax);
      float corr = __builtin_amdgcn_exp2f((m_run - m_new) * cL); // first tile: 0
      float co[4];
#pragma unroll
      for (int r = 0; r < 4; r++) co[r] = __shfl(corr, (lane & 48) | (g * 4 + r));
#pragma unroll
      for (int nd = 0; nd < 16; nd++) {
        o[nd][0] *= co[0]; o[nd][1] *= co[1]; o[nd][2] *= co[2]; o[nd][3] *= co[3];
      }
      l_run *= corr;
      m_run = m_new;
    }
    float mL = m_run * cL;
    float p[8], ps = 0.f;
#pragma unroll
    for (int i = 0; i < 8; i++) {
      p[i] = __builtin_amdgcn_exp2f(fmaf(sv[i], cL, -mL)); // bounded by 2^8
      ps += p[i];
    }
    ps += __shfl_xor(ps, 16);
    ps += __shfl_xor(ps, 32);
    l_run += ps;
    // P -> bf16 A-frag with key(g,i) = g*4 + (i&3) + 16*(i>>2); Vs slots hold V in the
    // same key order, so the B-fragment is ONE bh8 read (swizzled).
    bh8 pa;
#pragma unroll
    for (int i = 0; i < 8; i++) pa[i] = f2bf(p[i]);
#pragma unroll
    for (int nd = 0; nd < 16; nd++) {
      int d = nd * 16 + qr;
      bh8 vf = *(const bh8*)(Vs + (size_t)d * 32 + ((g ^ vsw) << 3));
      o[nd] = mfma16(pa, vf, o[nd]);
    }
  }

  float inv = 1.f / l_run;
  float io[4];
#pragma unroll
  for (int r = 0; r < 4; r++) io[r] = __shfl(inv, (lane & 48) | (g * 4 + r));
  __hip_bfloat16* zb = z + (size_t)b * SEQ * INNERW + hh * 256;
#pragma unroll
  for (int nd = 0; nd < 16; nd++)
#pragma unroll
    for (int r = 0; r < 4; r++)
      zb[(size_t)(q0 + g * 4 + r) * INNERW + nd * 16 + qr] = __float2bfloat16(o[nd][r] * io[r]);
}

// ---------------- host ----------------
extern "C" void kernel_launch(void* const* d_in, const int* in_sizes, int n_in,
                              void* d_out, int out_size, void* d_ws, size_t ws_size,
                              hipStream_t stream) {
  const float* x_in  = (const float*)d_in[0];
  const float* ln1g  = (const float*)d_in[1];
  const float* ln1b  = (const float*)d_in[2];
  const float* w_qkv = (const float*)d_in[3];
  const float* w_out = (const float*)d_in[4];
  const float* b_out = (const float*)d_in[5];
  const float* ln2g  = (const float*)d_in[6];
  const float* ln2b  = (const float*)d_in[7];
  const float* w1    = (const float*)d_in[8];
  const float* b1    = (const float*)d_in[9];
  const float* w2    = (const float*)d_in[10];
  const float* b2    = (const float*)d_in[11];

  char* ws = (char*)d_ws;
  size_t off = 0;
  auto alloc = [&](size_t bytes) { char* p = ws + off; off += (bytes + 255) & ~(size_t)255; return p; };
  float*          xf    = (float*)         alloc((size_t)ROWS * DM * 4);
  __hip_bfloat16* h     = (__hip_bfloat16*)alloc((size_t)ROWS * DM * 2);
  __hip_bfloat16* qkv   = (__hip_bfloat16*)alloc((size_t)ROWS * QKVW * 2);
  __hip_bfloat16* vT    = (__hip_bfloat16*)alloc((size_t)NB * NH * 256 * SEQ * 2);
  __hip_bfloat16* zbuf  = (__hip_bfloat16*)alloc((size_t)ROWS * INNERW * 2);
  __hip_bfloat16* mh    = zbuf; // MLP hidden reuses z region (disjoint lifetimes)
  __hip_bfloat16* wqkvT = (__hip_bfloat16*)alloc((size_t)NLAYER * QKVW * DM * 2);
  __hip_bfloat16* woutT = (__hip_bfloat16*)alloc((size_t)NLAYER * DM * INNERW * 2);
  __hip_bfloat16* w1T   = (__hip_bfloat16*)alloc((size_t)NLAYER * MLPD * DM * 2);
  __hip_bfloat16* w2T   = (__hip_bfloat16*)alloc((size_t)NLAYER * DM * MLPD * 2);
  (void)ws_size; (void)in_sizes; (void)n_in; (void)out_size;

  copy_f32_k<<<2048, 256, 0, stream>>>(x_in, xf);

  // weight transposes+casts (weights constant across the launch)
  wtrans_k<<<dim3(QKVW / 32, DM / 32, NLAYER), dim3(32, 8), 0, stream>>>(
      w_qkv, wqkvT, DM, QKVW, (size_t)DM * QKVW, (size_t)DM * QKVW);
  wtrans_k<<<dim3(DM / 32, INNERW / 32, NLAYER), dim3(32, 8), 0, stream>>>(
      w_out, woutT, INNERW, DM, (size_t)INNERW * DM, (size_t)INNERW * DM);
  wtrans_k<<<dim3(MLPD / 32, DM / 32, NLAYER), dim3(32, 8), 0, stream>>>(
      w1, w1T, DM, MLPD, (size_t)DM * MLPD, (size_t)DM * MLPD);
  wtrans_k<<<dim3(DM / 32, MLPD / 32, NLAYER), dim3(32, 8), 0, stream>>>(
      w2, w2T, MLPD, DM, (size_t)MLPD * DM, (size_t)MLPD * DM);

  for (int i = 0; i < NLAYER; i++) {
    ln_k<<<dim3(DM / 8, NB), 256, 0, stream>>>(xf, ln1g + i * SEQ, ln1b + i * SEQ, h);
    gemm_bt<128, 0><<<dim3(QKVW / 128, ROWS / 128), 256, 0, stream>>>(
        h, wqkvT + (size_t)i * QKVW * DM, qkv, nullptr, nullptr, ROWS, QKVW, DM);
    vtrans_k<<<dim3(SEQ / 64, 256 / 64, NB * NH), dim3(64, 8), 0, stream>>>(qkv, vT);
    attn_k<<<dim3(SEQ / 64, NH, NB), 256, 0, stream>>>(qkv, vT, zbuf);
    gemm_bt<64, 2><<<dim3(DM / 64, ROWS / 128), 256, 0, stream>>>(
        zbuf, woutT + (size_t)i * DM * INNERW, nullptr, b_out + i * DM, xf, ROWS, DM, INNERW);
    ln_k<<<dim3(DM / 8, NB), 256, 0, stream>>>(xf, ln2g + i * SEQ, ln2b + i * SEQ, h);
    gemm_bt<128, 1><<<dim3(MLPD / 128, ROWS / 128), 256, 0, stream>>>(
        h, w1T + (size_t)i * MLPD * DM, mh, b1 + i * MLPD, nullptr, ROWS, MLPD, DM);
    gemm_bt<64, 2><<<dim3(DM / 64, ROWS / 128), 256, 0, stream>>>(
        mh, w2T + (size_t)i * DM * MLPD, nullptr, b2 + i * DM, xf, ROWS, DM, MLPD);
  }

  copy_f32_k<<<2048, 256, 0, stream>>>(xf, (float*)d_out);
}